// Round 3
// baseline (343.242 us; speedup 1.0000x reference)
//
#include <hip/hip_runtime.h>
#include <hip/hip_bf16.h>

typedef unsigned short u16;
typedef __attribute__((ext_vector_type(8))) short short8;
typedef __attribute__((ext_vector_type(4))) float f32x4;

#define N_TOKENS 4096
#define HIDDEN   1024
#define N_EXP    8
#define EXPAND   2048

// ---------- workspace layout (bytes) ----------
#define TOKB_OFF  0ull                   // bf16 tokens      [4096][1024]    8,388,608
#define W1T_OFF   8388608ull             // bf16 w1^T        [8][2048][1024] 33,554,432
#define OBUF_OFF  8388608ull             // fp32 obuf        [8192][1024]    33,554,432 (reuses w1t after ffn1)
#define W2T_OFF   41943040ull            // bf16 w2^T        [8][1024][2048] 33,554,432
#define H_OFF     75497472ull            // bf16 h           [8192][2048]    33,554,432
#define RLT_OFF   109051904ull           // int rowlist_token[8192]
#define RLG_OFF   109084672ull           // float rowlist_gate[8192]
#define CNT_OFF   109117440ull           // int cnt[8]
#define E01_OFF   109117472ull           // int e01[4096][2]
#define SLOT_OFF  109150240ull           // int slots[4096][2]
#define GATE_OFF  109183008ull           // float gates[4096][2]
#define ROWS2_OFF 109215776ull           // int rows2[4096][2]

__device__ __forceinline__ u16 f2bf(float f) {
  union { float f; unsigned u; } v; v.f = f;
  unsigned r = v.u + 0x7fffu + ((v.u >> 16) & 1u);   // round-to-nearest-even
  return (u16)(r >> 16);
}

__device__ __forceinline__ void glds16(const void* g, void* l) {
  __builtin_amdgcn_global_load_lds(
      (const __attribute__((address_space(1))) void*)g,
      (__attribute__((address_space(3))) void*)l, 16, 0, 0);
}

__device__ __forceinline__ float gelu_tanh(float x) {
  // 0.5x(1+tanh(0.79788456(x+0.044715x^3))) ; |err vs erf-gelu| <~1e-3
  float u = x * (0.7978845608f + 0.0356774081f * x * x);
  float t = __expf(-2.0f * fabsf(u));
  float th = (1.0f - t) / (1.0f + t);
  th = (u >= 0.0f) ? th : -th;
  return 0.5f * x * (1.0f + th);
}

// expert -> (base, count) from cnt[8]
__device__ __forceinline__ void expert_range(const int* __restrict__ cnt, int e,
                                             int& m0, int& ne) {
  m0 = 0; ne = 0;
  #pragma unroll
  for (int i = 0; i < N_EXP; ++i) {
    int ci = cnt[i];
    if (i < e) m0 += ci;
    if (i == e) ne = ci;
  }
}

// ---------- tokens fp32 -> bf16 ----------
__global__ __launch_bounds__(256) void cvt_tokens_k(const float* __restrict__ in,
                                                    u16* __restrict__ out) {
  int i = blockIdx.x * 256 + threadIdx.x;
  const float4 v = ((const float4*)in)[i];
  ushort4 o;
  o.x = f2bf(v.x); o.y = f2bf(v.y); o.z = f2bf(v.z); o.w = f2bf(v.w);
  ((ushort4*)out)[i] = o;
}

// ---------- fp32 [E][R][C] -> bf16 [E][C][R] ----------
__global__ __launch_bounds__(256) void cvt_transpose_k(const float* __restrict__ in,
                                                       u16* __restrict__ out,
                                                       int R, int C) {
  __shared__ float t[32][33];
  int e = blockIdx.z;
  int r0 = blockIdx.y * 32, c0 = blockIdx.x * 32;
  const float* ip = in + (size_t)e * R * C;
  u16* op = out + (size_t)e * R * C;
  int tx = threadIdx.x, ty = threadIdx.y;
  #pragma unroll
  for (int i = 0; i < 4; ++i)
    t[ty + i * 8][tx] = ip[(size_t)(r0 + ty + i * 8) * C + c0 + tx];
  __syncthreads();
  #pragma unroll
  for (int i = 0; i < 4; ++i)
    op[(size_t)(c0 + ty + i * 8) * R + r0 + tx] = f2bf(t[tx][ty + i * 8]);
}

// ---------- router ----------
__global__ __launch_bounds__(256) void router_k(const float* __restrict__ tokens,
                                                const float* __restrict__ rw,
                                                const float* __restrict__ rb,
                                                int* __restrict__ e01,
                                                int* __restrict__ slots,
                                                float* __restrict__ gates,
                                                int* __restrict__ cnt) {
  __shared__ float rwl[N_EXP * HIDDEN];
  int tid = threadIdx.x;
  for (int i = tid; i < N_EXP * HIDDEN; i += 256) rwl[i] = rw[i];
  __syncthreads();
  int w = tid >> 6, l = tid & 63;
  int t = blockIdx.x * 4 + w;
  const float* tp = tokens + (size_t)t * HIDDEN;
  float acc[8] = {0.f,0.f,0.f,0.f,0.f,0.f,0.f,0.f};
  for (int k = l; k < HIDDEN; k += 64) {
    float tv = tp[k];
    #pragma unroll
    for (int e = 0; e < 8; ++e) acc[e] += tv * rwl[e * HIDDEN + k];
  }
  #pragma unroll
  for (int off = 32; off >= 1; off >>= 1) {
    #pragma unroll
    for (int e = 0; e < 8; ++e) acc[e] += __shfl_xor(acc[e], off);
  }
  if (l == 0) {
    float lg[8];
    #pragma unroll
    for (int e = 0; e < 8; ++e) lg[e] = acc[e] + rb[e];
    int b0 = 0; float v0 = lg[0];
    #pragma unroll
    for (int e = 1; e < 8; ++e) if (lg[e] > v0) { v0 = lg[e]; b0 = e; }
    int b1 = -1; float v1 = -3.4e38f;
    #pragma unroll
    for (int e = 0; e < 8; ++e) {
      if (e == b0) continue;
      if (lg[e] > v1) { v1 = lg[e]; b1 = e; }
    }
    float d = expf(v1 - v0);
    float p1 = d / (1.f + d);
    float p0 = 1.f - p1;
    int s0 = atomicAdd(&cnt[b0], 1);
    int s1 = atomicAdd(&cnt[b1], 1);
    e01[t * 2] = b0;   e01[t * 2 + 1] = b1;
    slots[t * 2] = s0; slots[t * 2 + 1] = s1;
    gates[t * 2] = p0; gates[t * 2 + 1] = p1;
  }
}

__global__ __launch_bounds__(256) void build_k(const int* __restrict__ e01,
                                               const int* __restrict__ slots,
                                               const float* __restrict__ gates,
                                               const int* __restrict__ cnt,
                                               int* __restrict__ rlt,
                                               float* __restrict__ rlg,
                                               int* __restrict__ rows2) {
  int t = blockIdx.x * 256 + threadIdx.x;
  if (t >= N_TOKENS) return;
  #pragma unroll
  for (int k = 0; k < 2; ++k) {
    int e = e01[t * 2 + k];
    int m0, ne;
    expert_range(cnt, e, m0, ne);
    int row = m0 + slots[t * 2 + k];
    rlt[row] = t;
    rlg[row] = gates[t * 2 + k];
    rows2[t * 2 + k] = row;
  }
}

// ---------- stage 1: h = gelu(tok_rows @ w1[e] + b1[e]) ----------
// BM=256 BN=256 BK=64, 512 thr / 8 waves (2M x 4N), wave tile 128x64.
// LDS 128 KB: A[2][256][64], B[2][256][64] bf16, XOR-chunk swizzled.
// 2-phase schedule: STAGE(t+1) -> ds_read(t)+MFMA -> vmcnt(0) -> barrier.
__global__ __launch_bounds__(512, 2) void ffn1_k(const u16* __restrict__ tok,
                                                 const u16* __restrict__ w1t,
                                                 const float* __restrict__ b1,
                                                 const int* __restrict__ rlt,
                                                 const int* __restrict__ cnt,
                                                 u16* __restrict__ h) {
  int e = blockIdx.z, mt = blockIdx.y, nt = blockIdx.x;
  int m0, ne;
  expert_range(cnt, e, m0, ne);
  if (mt * 256 >= ne) return;
  int m0g = m0 + mt * 256;
  int mrem = ne - mt * 256;

  __shared__ __align__(16) short Abuf[2][256 * 64];
  __shared__ __align__(16) short Bbuf[2][256 * 64];

  int tid = threadIdx.x, w = tid >> 6, l = tid & 63;
  int wr = w >> 2, wc = w & 3;               // 2 x 4 wave grid
  int lr = l & 15, lg = l >> 4;

  // staging addresses: round r covers rows r*64 .. r*64+63; thread -> 16B chunk
  int srow8 = tid >> 3;                      // 0..63 row-within-round
  int schunk = (tid & 7) ^ (srow8 & 7);      // pre-swizzled global chunk

  const u16* ga[4]; const u16* gb[4];
  #pragma unroll
  for (int r = 0; r < 4; ++r) {
    int row = r * 64 + srow8;                // 0..255
    int tokid = (row < mrem) ? rlt[m0g + row] : 0;
    ga[r] = tok + (size_t)tokid * HIDDEN + schunk * 8;
    int nrow = nt * 256 + row;
    gb[r] = w1t + (size_t)e * EXPAND * HIDDEN + (size_t)nrow * HIDDEN + schunk * 8;
  }

  const int NK = HIDDEN / 64;
  // prologue: stage kt=0 into buf 0, full drain
  #pragma unroll
  for (int r = 0; r < 4; ++r) {
    glds16(ga[r], &Abuf[0][r * 4096 + tid * 8]);
    glds16(gb[r], &Bbuf[0][r * 4096 + tid * 8]);
  }
  __syncthreads();

  f32x4 acc[8][4] = {};
  int cur = 0;
  for (int kt = 0; kt < NK; ++kt) {
    if (kt + 1 < NK) {
      int nb = cur ^ 1;
      #pragma unroll
      for (int r = 0; r < 4; ++r) {
        glds16(ga[r] + (kt + 1) * 64, &Abuf[nb][r * 4096 + tid * 8]);
        glds16(gb[r] + (kt + 1) * 64, &Bbuf[nb][r * 4096 + tid * 8]);
      }
    }
    #pragma unroll
    for (int kk = 0; kk < 2; ++kk) {
      int cc = kk * 4 + lg;
      short8 bfr[4], afr[8];
      #pragma unroll
      for (int j = 0; j < 4; ++j) {
        int R = wc * 64 + j * 16 + lr;
        bfr[j] = *(const short8*)&Bbuf[cur][R * 64 + (cc ^ (R & 7)) * 8];
      }
      #pragma unroll
      for (int i = 0; i < 8; ++i) {
        int R = wr * 128 + i * 16 + lr;
        afr[i] = *(const short8*)&Abuf[cur][R * 64 + (cc ^ (R & 7)) * 8];
      }
      __builtin_amdgcn_s_setprio(1);
      #pragma unroll
      for (int i = 0; i < 8; ++i)
        #pragma unroll
        for (int j = 0; j < 4; ++j)
          acc[i][j] = __builtin_amdgcn_mfma_f32_16x16x32_bf16(afr[i], bfr[j], acc[i][j], 0, 0, 0);
      __builtin_amdgcn_s_setprio(0);
    }
    asm volatile("s_waitcnt vmcnt(0)" ::: "memory");
    __builtin_amdgcn_s_barrier();
    __builtin_amdgcn_sched_barrier(0);
    cur ^= 1;
  }

  #pragma unroll
  for (int i = 0; i < 8; ++i) {
    #pragma unroll
    for (int r = 0; r < 4; ++r) {
      int row = wr * 128 + i * 16 + lg * 4 + r;
      if (row >= mrem) continue;
      size_t hrow = (size_t)(m0g + row) * EXPAND;
      #pragma unroll
      for (int j = 0; j < 4; ++j) {
        int col = nt * 256 + wc * 64 + j * 16 + lr;
        float x = acc[i][j][r] + b1[e * EXPAND + col];
        h[hrow + col] = f2bf(gelu_tanh(x));
      }
    }
  }
}

// ---------- stage 2: obuf[row] = gate * (h[row] @ w2[e] + b2[e]) ----------
// BM=128 BN=256 BK=64, 512 thr / 8 waves (2M x 4N), wave tile 64x64.
// LDS 96 KB: A[2][128][64], B[2][256][64].
__global__ __launch_bounds__(512, 2) void ffn2_k(const u16* __restrict__ h,
                                                 const u16* __restrict__ w2t,
                                                 const float* __restrict__ b2,
                                                 const float* __restrict__ rlg,
                                                 const int* __restrict__ cnt,
                                                 float* __restrict__ obuf) {
  int e = blockIdx.z, mt = blockIdx.y, nt = blockIdx.x;
  int m0, ne;
  expert_range(cnt, e, m0, ne);
  if (mt * 128 >= ne) return;
  int m0g = m0 + mt * 128;
  int mrem = ne - mt * 128;

  __shared__ __align__(16) short Abuf[2][128 * 64];
  __shared__ __align__(16) short Bbuf[2][256 * 64];

  int tid = threadIdx.x, w = tid >> 6, l = tid & 63;
  int wr = w >> 2, wc = w & 3;
  int lr = l & 15, lg = l >> 4;

  int srow8 = tid >> 3;
  int schunk = (tid & 7) ^ (srow8 & 7);

  const u16* ga[2]; const u16* gb[4];
  #pragma unroll
  for (int r = 0; r < 2; ++r) {
    int row = r * 64 + srow8;                // 0..127
    int rowg = m0g + ((row < mrem) ? row : 0);
    ga[r] = h + (size_t)rowg * EXPAND + schunk * 8;
  }
  #pragma unroll
  for (int r = 0; r < 4; ++r) {
    int nrow = nt * 256 + r * 64 + srow8;    // 0..1023 col index
    gb[r] = w2t + (size_t)e * HIDDEN * EXPAND + (size_t)nrow * EXPAND + schunk * 8;
  }

  const int NK = EXPAND / 64;
  #pragma unroll
  for (int r = 0; r < 2; ++r) glds16(ga[r], &Abuf[0][r * 4096 + tid * 8]);
  #pragma unroll
  for (int r = 0; r < 4; ++r) glds16(gb[r], &Bbuf[0][r * 4096 + tid * 8]);
  __syncthreads();

  f32x4 acc[4][4] = {};
  int cur = 0;
  for (int kt = 0; kt < NK; ++kt) {
    if (kt + 1 < NK) {
      int nb = cur ^ 1;
      #pragma unroll
      for (int r = 0; r < 2; ++r)
        glds16(ga[r] + (kt + 1) * 64, &Abuf[nb][r * 4096 + tid * 8]);
      #pragma unroll
      for (int r = 0; r < 4; ++r)
        glds16(gb[r] + (kt + 1) * 64, &Bbuf[nb][r * 4096 + tid * 8]);
    }
    #pragma unroll
    for (int kk = 0; kk < 2; ++kk) {
      int cc = kk * 4 + lg;
      short8 bfr[4], afr[4];
      #pragma unroll
      for (int j = 0; j < 4; ++j) {
        int R = wc * 64 + j * 16 + lr;
        bfr[j] = *(const short8*)&Bbuf[cur][R * 64 + (cc ^ (R & 7)) * 8];
      }
      #pragma unroll
      for (int i = 0; i < 4; ++i) {
        int R = wr * 64 + i * 16 + lr;
        afr[i] = *(const short8*)&Abuf[cur][R * 64 + (cc ^ (R & 7)) * 8];
      }
      __builtin_amdgcn_s_setprio(1);
      #pragma unroll
      for (int i = 0; i < 4; ++i)
        #pragma unroll
        for (int j = 0; j < 4; ++j)
          acc[i][j] = __builtin_amdgcn_mfma_f32_16x16x32_bf16(afr[i], bfr[j], acc[i][j], 0, 0, 0);
      __builtin_amdgcn_s_setprio(0);
    }
    asm volatile("s_waitcnt vmcnt(0)" ::: "memory");
    __builtin_amdgcn_s_barrier();
    __builtin_amdgcn_sched_barrier(0);
    cur ^= 1;
  }

  #pragma unroll
  for (int i = 0; i < 4; ++i) {
    #pragma unroll
    for (int r = 0; r < 4; ++r) {
      int row = wr * 64 + i * 16 + lg * 4 + r;
      if (row >= mrem) continue;
      float gate = rlg[m0g + row];
      size_t orow = (size_t)(m0g + row) * HIDDEN;
      #pragma unroll
      for (int j = 0; j < 4; ++j) {
        int col = nt * 256 + wc * 64 + j * 16 + lr;
        obuf[orow + col] = (acc[i][j][r] + b2[e * HIDDEN + col]) * gate;
      }
    }
  }
}

// ---------- combine: out[t] = obuf[row0(t)] + obuf[row1(t)] ----------
__global__ __launch_bounds__(256) void combine_k(const float* __restrict__ obuf,
                                                 const int* __restrict__ rows2,
                                                 float* __restrict__ out) {
  int t = blockIdx.x, c = threadIdx.x;
  int r0 = rows2[t * 2], r1 = rows2[t * 2 + 1];
  float4 a = ((const float4*)obuf)[(size_t)r0 * 256 + c];
  float4 b = ((const float4*)obuf)[(size_t)r1 * 256 + c];
  float4 o;
  o.x = a.x + b.x; o.y = a.y + b.y; o.z = a.z + b.z; o.w = a.w + b.w;
  ((float4*)out)[(size_t)t * 256 + c] = o;
}

extern "C" void kernel_launch(void* const* d_in, const int* in_sizes, int n_in,
                              void* d_out, int out_size, void* d_ws, size_t ws_size,
                              hipStream_t stream) {
  const float* tokens   = (const float*)d_in[0];
  const float* router_w = (const float*)d_in[1];
  const float* router_b = (const float*)d_in[2];
  const float* w1       = (const float*)d_in[3];
  const float* b1       = (const float*)d_in[4];
  const float* w2       = (const float*)d_in[5];
  const float* b2       = (const float*)d_in[6];
  float* out = (float*)d_out;

  char* ws = (char*)d_ws;
  u16*   tokb  = (u16*)(ws + TOKB_OFF);
  u16*   w1t   = (u16*)(ws + W1T_OFF);
  float* obuf  = (float*)(ws + OBUF_OFF);
  u16*   w2t   = (u16*)(ws + W2T_OFF);
  u16*   h     = (u16*)(ws + H_OFF);
  int*   rlt   = (int*)(ws + RLT_OFF);
  float* rlg   = (float*)(ws + RLG_OFF);
  int*   cnt   = (int*)(ws + CNT_OFF);
  int*   e01   = (int*)(ws + E01_OFF);
  int*   slots = (int*)(ws + SLOT_OFF);
  float* gates = (float*)(ws + GATE_OFF);
  int*   rows2 = (int*)(ws + ROWS2_OFF);

  hipMemsetAsync(cnt, 0, 32, stream);

  cvt_tokens_k<<<(N_TOKENS * HIDDEN / 4) / 256, 256, 0, stream>>>(tokens, tokb);
  cvt_transpose_k<<<dim3(EXPAND / 32, HIDDEN / 32, N_EXP), dim3(32, 8), 0, stream>>>(
      w1, w1t, HIDDEN, EXPAND);
  cvt_transpose_k<<<dim3(HIDDEN / 32, EXPAND / 32, N_EXP), dim3(32, 8), 0, stream>>>(
      w2, w2t, EXPAND, HIDDEN);
  router_k<<<N_TOKENS / 4, 256, 0, stream>>>(tokens, router_w, router_b,
                                             e01, slots, gates, cnt);
  build_k<<<N_TOKENS / 256, 256, 0, stream>>>(e01, slots, gates, cnt, rlt, rlg, rows2);
  ffn1_k<<<dim3(EXPAND / 256, 16, N_EXP), 512, 0, stream>>>(tokb, w1t, b1, rlt, cnt, h);
  ffn2_k<<<dim3(HIDDEN / 256, 32, N_EXP), 512, 0, stream>>>(h, w2t, b2, rlg, cnt, obuf);
  combine_k<<<N_TOKENS, 256, 0, stream>>>(obuf, rows2, out);
}

// Round 4
// 260.289 us; speedup vs baseline: 1.3187x; 1.3187x over previous
//
#include <hip/hip_runtime.h>
#include <hip/hip_bf16.h>

typedef unsigned short u16;
typedef __attribute__((ext_vector_type(8))) short short8;
typedef __attribute__((ext_vector_type(4))) float f32x4;

#define N_TOKENS 4096
#define HIDDEN   1024
#define N_EXP    8
#define EXPAND   2048

// ---------- workspace layout (bytes) ----------
#define TOKB_OFF  0ull                   // bf16 tokens      [4096][1024]    8,388,608
#define W1T_OFF   8388608ull             // bf16 w1^T        [8][2048][1024] 33,554,432
#define OBUF_OFF  8388608ull             // fp32 obuf        [8192][1024]    33,554,432 (reuses w1t after ffn1)
#define W2T_OFF   41943040ull            // bf16 w2^T        [8][1024][2048] 33,554,432
#define H_OFF     75497472ull            // bf16 h           [8192][2048]    33,554,432
#define RLT_OFF   109051904ull           // int rowlist_token[8192]
#define RLG_OFF   109084672ull           // float rowlist_gate[8192]
#define CNT_OFF   109117440ull           // int cnt[8]
#define E01_OFF   109117472ull           // int e01[4096][2]
#define GATE_OFF  109183008ull           // float gates[4096][2]
#define ROWS2_OFF 109215776ull           // int rows2[4096][2]

__device__ __forceinline__ u16 f2bf(float f) {
  union { float f; unsigned u; } v; v.f = f;
  unsigned r = v.u + 0x7fffu + ((v.u >> 16) & 1u);   // round-to-nearest-even
  return (u16)(r >> 16);
}

__device__ __forceinline__ void glds16(const void* g, void* l) {
  __builtin_amdgcn_global_load_lds(
      (const __attribute__((address_space(1))) void*)g,
      (__attribute__((address_space(3))) void*)l, 16, 0, 0);
}

__device__ __forceinline__ float gelu_tanh(float x) {
  float u = x * (0.7978845608f + 0.0356774081f * x * x);
  float t = __expf(-2.0f * fabsf(u));
  float th = (1.0f - t) / (1.0f + t);
  th = (u >= 0.0f) ? th : -th;
  return 0.5f * x * (1.0f + th);
}

// expert -> (base, count) from cnt[8]
__device__ __forceinline__ void expert_range(const int* __restrict__ cnt, int e,
                                             int& m0, int& ne) {
  m0 = 0; ne = 0;
  #pragma unroll
  for (int i = 0; i < N_EXP; ++i) {
    int ci = cnt[i];
    if (i < e) m0 += ci;
    if (i == e) ne = ci;
  }
}

// ---------- tokens fp32 -> bf16 ----------
__global__ __launch_bounds__(256) void cvt_tokens_k(const float* __restrict__ in,
                                                    u16* __restrict__ out) {
  int i = blockIdx.x * 256 + threadIdx.x;
  const float4 v = ((const float4*)in)[i];
  ushort4 o;
  o.x = f2bf(v.x); o.y = f2bf(v.y); o.z = f2bf(v.z); o.w = f2bf(v.w);
  ((ushort4*)out)[i] = o;
}

// ---------- fp32 [E][R][C] -> bf16 [E][C][R] ----------
__global__ __launch_bounds__(256) void cvt_transpose_k(const float* __restrict__ in,
                                                       u16* __restrict__ out,
                                                       int R, int C) {
  __shared__ float t[32][33];
  int e = blockIdx.z;
  int r0 = blockIdx.y * 32, c0 = blockIdx.x * 32;
  const float* ip = in + (size_t)e * R * C;
  u16* op = out + (size_t)e * R * C;
  int tx = threadIdx.x, ty = threadIdx.y;
  #pragma unroll
  for (int i = 0; i < 4; ++i)
    t[ty + i * 8][tx] = ip[(size_t)(r0 + ty + i * 8) * C + c0 + tx];
  __syncthreads();
  #pragma unroll
  for (int i = 0; i < 4; ++i)
    op[(size_t)(c0 + ty + i * 8) * R + r0 + tx] = f2bf(t[tx][ty + i * 8]);
}

// ---------- logits + top-2 + softmax (NO atomics) ----------
__global__ __launch_bounds__(256) void logits_k(const float* __restrict__ tokens,
                                                const float* __restrict__ rw,
                                                const float* __restrict__ rb,
                                                int* __restrict__ e01,
                                                float* __restrict__ gates) {
  __shared__ float rwl[N_EXP * HIDDEN];
  int tid = threadIdx.x;
  for (int i = tid; i < N_EXP * HIDDEN; i += 256) rwl[i] = rw[i];
  __syncthreads();
  int w = tid >> 6, l = tid & 63;
  int t = blockIdx.x * 4 + w;
  const float* tp = tokens + (size_t)t * HIDDEN;
  float acc[8] = {0.f,0.f,0.f,0.f,0.f,0.f,0.f,0.f};
  for (int k = l; k < HIDDEN; k += 64) {
    float tv = tp[k];
    #pragma unroll
    for (int e = 0; e < 8; ++e) acc[e] += tv * rwl[e * HIDDEN + k];
  }
  #pragma unroll
  for (int off = 32; off >= 1; off >>= 1) {
    #pragma unroll
    for (int e = 0; e < 8; ++e) acc[e] += __shfl_xor(acc[e], off);
  }
  if (l == 0) {
    float lg[8];
    #pragma unroll
    for (int e = 0; e < 8; ++e) lg[e] = acc[e] + rb[e];
    int b0 = 0; float v0 = lg[0];
    #pragma unroll
    for (int e = 1; e < 8; ++e) if (lg[e] > v0) { v0 = lg[e]; b0 = e; }
    int b1 = -1; float v1 = -3.4e38f;
    #pragma unroll
    for (int e = 0; e < 8; ++e) {
      if (e == b0) continue;
      if (lg[e] > v1) { v1 = lg[e]; b1 = e; }
    }
    float d = expf(v1 - v0);
    float p1 = d / (1.f + d);
    float p0 = 1.f - p1;
    e01[t * 2] = b0;   e01[t * 2 + 1] = b1;
    gates[t * 2] = p0; gates[t * 2 + 1] = p1;
  }
}

// ---------- deterministic stable counting sort by expert (single block) ----------
// 8192 entries (token,k), 1024 threads, 8 chunks. Ballot rank + 16x8 LDS scan.
__global__ __launch_bounds__(1024) void order_k(const int* __restrict__ e01,
                                                const float* __restrict__ gates,
                                                int* __restrict__ cnt,
                                                int* __restrict__ rlt,
                                                float* __restrict__ rlg,
                                                int* __restrict__ rows2) {
  __shared__ int slotbuf[2 * N_TOKENS];
  __shared__ int wcnt[16][N_EXP];
  __shared__ int base_run[N_EXP];
  __shared__ int basep[N_EXP];
  int tid = threadIdx.x, w = tid >> 6, l = tid & 63;
  if (tid < N_EXP) base_run[tid] = 0;
  __syncthreads();
  unsigned long long ltmask = (1ull << l) - 1ull;
  #pragma unroll
  for (int c = 0; c < 8; ++c) {
    int i = c * 1024 + tid;
    int ei = e01[i];
    int myrank = 0;
    #pragma unroll
    for (int e = 0; e < N_EXP; ++e) {
      unsigned long long b = __ballot(ei == e);
      if (l == 0) wcnt[w][e] = __popcll(b);
      if (ei == e) myrank = __popcll(b & ltmask);
    }
    __syncthreads();
    if (tid < N_EXP) {
      int e = tid, off = base_run[e];
      #pragma unroll
      for (int ww = 0; ww < 16; ++ww) {
        int v = wcnt[ww][e]; wcnt[ww][e] = off; off += v;
      }
      base_run[e] = off;
    }
    __syncthreads();
    slotbuf[i] = wcnt[w][ei] + myrank;
    __syncthreads();
  }
  if (tid < N_EXP) cnt[tid] = base_run[tid];
  if (tid == 0) {
    int s = 0;
    for (int e = 0; e < N_EXP; ++e) { basep[e] = s; s += base_run[e]; }
  }
  __syncthreads();
  #pragma unroll
  for (int c = 0; c < 8; ++c) {
    int i = c * 1024 + tid;
    int e = e01[i];
    int row = basep[e] + slotbuf[i];
    rlt[row] = i >> 1;
    rlg[row] = gates[i];
    rows2[i] = row;
  }
}

// ---------- stage 1: h = gelu(tok_rows @ w1[e] + b1[e]) ----------
// BM=256 BN=256 BK=64, 512 thr / 8 waves (2M x 4N), wave tile 128x64.
__global__ __launch_bounds__(512, 2) void ffn1_k(const u16* __restrict__ tok,
                                                 const u16* __restrict__ w1t,
                                                 const float* __restrict__ b1,
                                                 const int* __restrict__ rlt,
                                                 const int* __restrict__ cnt,
                                                 u16* __restrict__ h) {
  int e = blockIdx.z, mt = blockIdx.y, nt = blockIdx.x;
  int m0, ne;
  expert_range(cnt, e, m0, ne);
  if (mt * 256 >= ne) return;
  int m0g = m0 + mt * 256;
  int mrem = ne - mt * 256;

  __shared__ __align__(16) short Abuf[2][256 * 64];
  __shared__ __align__(16) short Bbuf[2][256 * 64];

  int tid = threadIdx.x, w = tid >> 6, l = tid & 63;
  int wr = w >> 2, wc = w & 3;
  int lr = l & 15, lg = l >> 4;

  int srow8 = tid >> 3;
  int schunk = (tid & 7) ^ (srow8 & 7);

  const u16* ga[4]; const u16* gb[4];
  #pragma unroll
  for (int r = 0; r < 4; ++r) {
    int row = r * 64 + srow8;
    int tokid = (row < mrem) ? rlt[m0g + row] : 0;
    ga[r] = tok + (size_t)tokid * HIDDEN + schunk * 8;
    int nrow = nt * 256 + row;
    gb[r] = w1t + (size_t)e * EXPAND * HIDDEN + (size_t)nrow * HIDDEN + schunk * 8;
  }

  const int NK = HIDDEN / 64;
  #pragma unroll
  for (int r = 0; r < 4; ++r) {
    glds16(ga[r], &Abuf[0][r * 4096 + tid * 8]);
    glds16(gb[r], &Bbuf[0][r * 4096 + tid * 8]);
  }
  __syncthreads();

  f32x4 acc[8][4] = {};
  int cur = 0;
  for (int kt = 0; kt < NK; ++kt) {
    if (kt + 1 < NK) {
      int nb = cur ^ 1;
      #pragma unroll
      for (int r = 0; r < 4; ++r) {
        glds16(ga[r] + (kt + 1) * 64, &Abuf[nb][r * 4096 + tid * 8]);
        glds16(gb[r] + (kt + 1) * 64, &Bbuf[nb][r * 4096 + tid * 8]);
      }
    }
    #pragma unroll
    for (int kk = 0; kk < 2; ++kk) {
      int cc = kk * 4 + lg;
      short8 bfr[4], afr[8];
      #pragma unroll
      for (int j = 0; j < 4; ++j) {
        int R = wc * 64 + j * 16 + lr;
        bfr[j] = *(const short8*)&Bbuf[cur][R * 64 + (cc ^ (R & 7)) * 8];
      }
      #pragma unroll
      for (int i = 0; i < 8; ++i) {
        int R = wr * 128 + i * 16 + lr;
        afr[i] = *(const short8*)&Abuf[cur][R * 64 + (cc ^ (R & 7)) * 8];
      }
      __builtin_amdgcn_s_setprio(1);
      #pragma unroll
      for (int i = 0; i < 8; ++i)
        #pragma unroll
        for (int j = 0; j < 4; ++j)
          acc[i][j] = __builtin_amdgcn_mfma_f32_16x16x32_bf16(afr[i], bfr[j], acc[i][j], 0, 0, 0);
      __builtin_amdgcn_s_setprio(0);
    }
    asm volatile("s_waitcnt vmcnt(0)" ::: "memory");
    __builtin_amdgcn_s_barrier();
    __builtin_amdgcn_sched_barrier(0);
    cur ^= 1;
  }

  #pragma unroll
  for (int i = 0; i < 8; ++i) {
    #pragma unroll
    for (int r = 0; r < 4; ++r) {
      int row = wr * 128 + i * 16 + lg * 4 + r;
      if (row >= mrem) continue;
      size_t hrow = (size_t)(m0g + row) * EXPAND;
      #pragma unroll
      for (int j = 0; j < 4; ++j) {
        int col = nt * 256 + wc * 64 + j * 16 + lr;
        float x = acc[i][j][r] + b1[e * EXPAND + col];
        h[hrow + col] = f2bf(gelu_tanh(x));
      }
    }
  }
}

// ---------- stage 2: obuf[row] = gate * (h[row] @ w2[e] + b2[e]) ----------
// BM=128 BN=256 BK=64, 512 thr / 8 waves (2M x 4N), wave tile 64x64.
__global__ __launch_bounds__(512, 2) void ffn2_k(const u16* __restrict__ h,
                                                 const u16* __restrict__ w2t,
                                                 const float* __restrict__ b2,
                                                 const float* __restrict__ rlg,
                                                 const int* __restrict__ cnt,
                                                 float* __restrict__ obuf) {
  int e = blockIdx.z, mt = blockIdx.y, nt = blockIdx.x;
  int m0, ne;
  expert_range(cnt, e, m0, ne);
  if (mt * 128 >= ne) return;
  int m0g = m0 + mt * 128;
  int mrem = ne - mt * 128;

  __shared__ __align__(16) short Abuf[2][128 * 64];
  __shared__ __align__(16) short Bbuf[2][256 * 64];

  int tid = threadIdx.x, w = tid >> 6, l = tid & 63;
  int wr = w >> 2, wc = w & 3;
  int lr = l & 15, lg = l >> 4;

  int srow8 = tid >> 3;
  int schunk = (tid & 7) ^ (srow8 & 7);

  const u16* ga[2]; const u16* gb[4];
  #pragma unroll
  for (int r = 0; r < 2; ++r) {
    int row = r * 64 + srow8;
    int rowg = m0g + ((row < mrem) ? row : 0);
    ga[r] = h + (size_t)rowg * EXPAND + schunk * 8;
  }
  #pragma unroll
  for (int r = 0; r < 4; ++r) {
    int nrow = nt * 256 + r * 64 + srow8;
    gb[r] = w2t + (size_t)e * HIDDEN * EXPAND + (size_t)nrow * EXPAND + schunk * 8;
  }

  const int NK = EXPAND / 64;
  #pragma unroll
  for (int r = 0; r < 2; ++r) glds16(ga[r], &Abuf[0][r * 4096 + tid * 8]);
  #pragma unroll
  for (int r = 0; r < 4; ++r) glds16(gb[r], &Bbuf[0][r * 4096 + tid * 8]);
  __syncthreads();

  f32x4 acc[4][4] = {};
  int cur = 0;
  for (int kt = 0; kt < NK; ++kt) {
    if (kt + 1 < NK) {
      int nb = cur ^ 1;
      #pragma unroll
      for (int r = 0; r < 2; ++r)
        glds16(ga[r] + (kt + 1) * 64, &Abuf[nb][r * 4096 + tid * 8]);
      #pragma unroll
      for (int r = 0; r < 4; ++r)
        glds16(gb[r] + (kt + 1) * 64, &Bbuf[nb][r * 4096 + tid * 8]);
    }
    #pragma unroll
    for (int kk = 0; kk < 2; ++kk) {
      int cc = kk * 4 + lg;
      short8 bfr[4], afr[4];
      #pragma unroll
      for (int j = 0; j < 4; ++j) {
        int R = wc * 64 + j * 16 + lr;
        bfr[j] = *(const short8*)&Bbuf[cur][R * 64 + (cc ^ (R & 7)) * 8];
      }
      #pragma unroll
      for (int i = 0; i < 4; ++i) {
        int R = wr * 64 + i * 16 + lr;
        afr[i] = *(const short8*)&Abuf[cur][R * 64 + (cc ^ (R & 7)) * 8];
      }
      __builtin_amdgcn_s_setprio(1);
      #pragma unroll
      for (int i = 0; i < 4; ++i)
        #pragma unroll
        for (int j = 0; j < 4; ++j)
          acc[i][j] = __builtin_amdgcn_mfma_f32_16x16x32_bf16(afr[i], bfr[j], acc[i][j], 0, 0, 0);
      __builtin_amdgcn_s_setprio(0);
    }
    asm volatile("s_waitcnt vmcnt(0)" ::: "memory");
    __builtin_amdgcn_s_barrier();
    __builtin_amdgcn_sched_barrier(0);
    cur ^= 1;
  }

  #pragma unroll
  for (int i = 0; i < 4; ++i) {
    #pragma unroll
    for (int r = 0; r < 4; ++r) {
      int row = wr * 64 + i * 16 + lg * 4 + r;
      if (row >= mrem) continue;
      float gate = rlg[m0g + row];
      size_t orow = (size_t)(m0g + row) * HIDDEN;
      #pragma unroll
      for (int j = 0; j < 4; ++j) {
        int col = nt * 256 + wc * 64 + j * 16 + lr;
        obuf[orow + col] = (acc[i][j][r] + b2[e * HIDDEN + col]) * gate;
      }
    }
  }
}

// ---------- combine: out[t] = obuf[row0(t)] + obuf[row1(t)] ----------
__global__ __launch_bounds__(256) void combine_k(const float* __restrict__ obuf,
                                                 const int* __restrict__ rows2,
                                                 float* __restrict__ out) {
  int t = blockIdx.x, c = threadIdx.x;
  int r0 = rows2[t * 2], r1 = rows2[t * 2 + 1];
  float4 a = ((const float4*)obuf)[(size_t)r0 * 256 + c];
  float4 b = ((const float4*)obuf)[(size_t)r1 * 256 + c];
  float4 o;
  o.x = a.x + b.x; o.y = a.y + b.y; o.z = a.z + b.z; o.w = a.w + b.w;
  ((float4*)out)[(size_t)t * 256 + c] = o;
}

extern "C" void kernel_launch(void* const* d_in, const int* in_sizes, int n_in,
                              void* d_out, int out_size, void* d_ws, size_t ws_size,
                              hipStream_t stream) {
  const float* tokens   = (const float*)d_in[0];
  const float* router_w = (const float*)d_in[1];
  const float* router_b = (const float*)d_in[2];
  const float* w1       = (const float*)d_in[3];
  const float* b1       = (const float*)d_in[4];
  const float* w2       = (const float*)d_in[5];
  const float* b2       = (const float*)d_in[6];
  float* out = (float*)d_out;

  char* ws = (char*)d_ws;
  u16*   tokb  = (u16*)(ws + TOKB_OFF);
  u16*   w1t   = (u16*)(ws + W1T_OFF);
  float* obuf  = (float*)(ws + OBUF_OFF);
  u16*   w2t   = (u16*)(ws + W2T_OFF);
  u16*   h     = (u16*)(ws + H_OFF);
  int*   rlt   = (int*)(ws + RLT_OFF);
  float* rlg   = (float*)(ws + RLG_OFF);
  int*   cnt   = (int*)(ws + CNT_OFF);
  int*   e01   = (int*)(ws + E01_OFF);
  float* gates = (float*)(ws + GATE_OFF);
  int*   rows2 = (int*)(ws + ROWS2_OFF);

  cvt_tokens_k<<<(N_TOKENS * HIDDEN / 4) / 256, 256, 0, stream>>>(tokens, tokb);
  cvt_transpose_k<<<dim3(EXPAND / 32, HIDDEN / 32, N_EXP), dim3(32, 8), 0, stream>>>(
      w1, w1t, HIDDEN, EXPAND);
  cvt_transpose_k<<<dim3(HIDDEN / 32, EXPAND / 32, N_EXP), dim3(32, 8), 0, stream>>>(
      w2, w2t, EXPAND, HIDDEN);
  logits_k<<<N_TOKENS / 4, 256, 0, stream>>>(tokens, router_w, router_b, e01, gates);
  order_k<<<1, 1024, 0, stream>>>(e01, gates, cnt, rlt, rlg, rows2);
  ffn1_k<<<dim3(EXPAND / 256, 16, N_EXP), 512, 0, stream>>>(tokb, w1t, b1, rlt, cnt, h);
  ffn2_k<<<dim3(HIDDEN / 256, 32, N_EXP), 512, 0, stream>>>(h, w2t, b2, rlg, cnt, obuf);
  combine_k<<<N_TOKENS, 256, 0, stream>>>(obuf, rows2, out);
}